// Round 4
// baseline (135.804 us; speedup 1.0000x reference)
//
#include <hip/hip_runtime.h>
#include <hip/hip_bf16.h>

#define N_NODES 50000
#define DIM 64
#define N_EDGES 800000
#define CAP 64          // padded-CSR capacity; P(deg>64) for Poisson(16) ~ e^-125
#define NTHR 256
#define GB_ROWS 32      // y-GEMM rows per block
#define SLICE 6250      // N_NODES / 8 rows per XCD slice (K2 mapping only)
#define NGROUP 196      // 24-block groups: 8 GEMM + 16 place
#define TOTAL_BLOCKS (NGROUP * 24)      // 4704

// ws layout: count[N_NODES] ints @0; yb = bf16 y[N_NODES*DIM] @256KB.
// csr[N_NODES*CAP] ints aliases d_out.
// Budget model (R0-R3 evidence): dur_us includes ~92us of harness poison
// fills; addressable ~= 37us = memset/launch ~5 + K1 ~20 + K2 ~12.

typedef __attribute__((ext_vector_type(8))) short bf16x8;   // 8 bf16 (4 VGPRs)
typedef __attribute__((ext_vector_type(4))) float f32x4;    // 4 fp32 acc

static __device__ inline unsigned int f2bf(float f) {
    __hip_bfloat16 h = __float2bfloat16(f);           // RNE
    return (unsigned int)*reinterpret_cast<unsigned short*>(&h);
}
static __device__ inline float bf_lo(unsigned int u) { return __uint_as_float(u << 16); }
static __device__ inline float bf_hi(unsigned int u) { return __uint_as_float(u & 0xffff0000u); }

// K1 (interleaved block-specialization):
//   b%24 <  8 -> y = x @ W^T via v_mfma_f32_16x16x32_bf16 (32 rows/block).
//                x hi/lo-split (bf16 pair) => fp32-x * bf16-W in fp32 acc.
//   b%24 >= 8 -> place: 1 edge/thread, fully coalesced row+col loads,
//                1 fetch-add + 1 csr store. [R4: dropped the 8x slice-filter
//                chunk replication — 51MB of redundant reads -> 6.4MB; atomics
//                are device-scope (coherence-point) regardless of XCD, and
//                cross-XCD csr same-line stores are safe via byte-masked
//                writebacks, which the old undefined bid->XCD heuristic
//                already relied on.]
// [R2 lesson: do NOT merge phases into one kernel — regalloc collapsed to
//  VGPR=24 with scratch spills, 3.5x regression.]
// [R3 lesson: two-phase col-partitioned gather costs more loop VALU than the
//  L2 residency returns — K2 loop ~6us total.]
__global__ __launch_bounds__(NTHR, 8) void place_gemm_kernel(
    const int* __restrict__ ei, const float* __restrict__ x,
    const float* __restrict__ W, int* __restrict__ count,
    int* csr, unsigned short* __restrict__ yb)
{
    __shared__ float4 xs4[GB_ROWS * 16];    // 8 KB fp32 x rows, slot c^(m&15)
    __shared__ uint4  Wb[512];              // 8 KB bf16 W, [n][kg^(n&7)] short8

    int t = threadIdx.x;
    int b = blockIdx.x;
    int m = b % 24;

    if (m < 8) {
        // ---- y-GEMM side: g = (b/24)*8 + m in [0, 1568); active g < 1563 ----
        int g  = (b / 24) * 8 + m;
        int R0 = g * GB_ROWS;
        if (R0 < N_NODES) {                 // block-uniform; tail slots exit
            const float4* x4 = (const float4*)x;
            for (int i = t; i < GB_ROWS * 16; i += NTHR) {
                int r = i >> 4, c = i & 15;
                int q = (R0 + r) * 16 + c;
                float4 v = (q < N_NODES * 16) ? x4[q]
                                              : make_float4(0.f, 0.f, 0.f, 0.f);
                xs4[(r << 4) | (c ^ (r & 15))] = v;     // XOR-swizzled slot
            }
            for (int i = t; i < 512; i += NTHR) {       // W: n=i>>3, kgrp=i&7
                int n = i >> 3, kg = i & 7;
                const float* wr = W + n * DIM + kg * 8; // 8 contiguous k
                uint4 uw;
                uw.x = f2bf(wr[0]) | (f2bf(wr[1]) << 16);
                uw.y = f2bf(wr[2]) | (f2bf(wr[3]) << 16);
                uw.z = f2bf(wr[4]) | (f2bf(wr[5]) << 16);
                uw.w = f2bf(wr[6]) | (f2bf(wr[7]) << 16);
                Wb[(n << 3) | (kg ^ (n & 7))] = uw;     // XOR-swizzled slot
            }
            __syncthreads();

            int w  = t >> 6, l = t & 63;
            int rt = w >> 1, ch = w & 1;    // row-tile (16 rows), col-half (32)
            int lm = l & 15, lg = l >> 4;   // frag row/col lane, k-group lane
            int mloc = rt * 16 + lm;        // local A row 0..31

            f32x4 acc0 = {0.f, 0.f, 0.f, 0.f};
            f32x4 acc1 = {0.f, 0.f, 0.f, 0.f};
#pragma unroll
            for (int kc = 0; kc < 2; kc++) {            // K = 64 in 2 chunks
                int c0 = kc * 8 + lg * 2;               // float4 slot index
                float4 xa = xs4[(mloc << 4) | ((c0    ) ^ lm)];
                float4 xb = xs4[(mloc << 4) | ((c0 + 1) ^ lm)];
                float xv[8] = {xa.x, xa.y, xa.z, xa.w, xb.x, xb.y, xb.z, xb.w};
                bf16x8 ahi, alo;                        // hi/lo split of x
#pragma unroll
                for (int j = 0; j < 8; j++) {
                    unsigned hb = f2bf(xv[j]);
                    float lo = xv[j] - __uint_as_float(hb << 16);
                    ahi[j] = (short)hb;
                    alo[j] = (short)f2bf(lo);
                }
                int kgg = kc * 4 + lg;                  // global k-group 0..7
#pragma unroll
                for (int ctl = 0; ctl < 2; ctl++) {     // 2 col-tiles per wave
                    int n = (ch * 2 + ctl) * 16 + lm;   // B col == W row
                    uint4 wq = Wb[(n << 3) | (kgg ^ (n & 7))];
                    bf16x8 bfr = *reinterpret_cast<bf16x8*>(&wq);
                    if (ctl == 0) {
                        acc0 = __builtin_amdgcn_mfma_f32_16x16x32_bf16(ahi, bfr, acc0, 0, 0, 0);
                        acc0 = __builtin_amdgcn_mfma_f32_16x16x32_bf16(alo, bfr, acc0, 0, 0, 0);
                    } else {
                        acc1 = __builtin_amdgcn_mfma_f32_16x16x32_bf16(ahi, bfr, acc1, 0, 0, 0);
                        acc1 = __builtin_amdgcn_mfma_f32_16x16x32_bf16(alo, bfr, acc1, 0, 0, 0);
                    }
                }
            }
            // C/D layout: col = lane&15, row = (lane>>4)*4 + reg  [m89/m91]
#pragma unroll
            for (int ctl = 0; ctl < 2; ctl++) {
                f32x4 acc = ctl ? acc1 : acc0;
                int n = (ch * 2 + ctl) * 16 + lm;
#pragma unroll
                for (int q = 0; q < 4; q++) {
                    int rr = R0 + rt * 16 + lg * 4 + q;
                    if (rr < N_NODES)
                        yb[(size_t)rr * DIM + n] = (unsigned short)f2bf(acc[q]);
                }
            }
        }
    } else {
        // ---- place side: p = (b/24)*16 + (m-8) in [0,3136); 1 edge/thread --
        int p = (b / 24) * 16 + (m - 8);
        int e = p * NTHR + t;               // coalesced row+col streams
        if (e < N_EDGES) {
            int row = ei[e];
            int col = ei[N_EDGES + e];
            int pos = atomicAdd(&count[row], 1);
            if (pos < CAP) csr[row * CAP + pos] = col;
        }
    }
}

// K2: gather-mean over bf16 y + bias. 1 row/wave, slice-mapped (sb=bid&7)
// so out/csr/count traffic stays loosely XCD-affine. Gather software-
// pipelined 2-deep. csr aliases out: all 64 lanes load the row's 256B csr
// chunk before lanes 0-7's stores overwrite that region.
__global__ __launch_bounds__(NTHR) void agg_kernel(
    const unsigned short* __restrict__ yb, const int* __restrict__ count,
    const int* csr, const float* __restrict__ bias, float* out)
{
    int t   = threadIdx.x;
    int w   = t >> 6;
    int l   = t & 63;
    int sub = l & 7;                    // which 16B (8 feats) of the 128B row
    int grp = l >> 3;                   // edge group 0..7
    int sb  = blockIdx.x & 7;           // row slice
    int i   = blockIdx.x >> 3;          // 0..1562
    int rl  = i * 4 + w;
    if (rl >= SLICE) return;            // tail guard
    int r = sb * SLICE + rl;

    int deg = count[r];
    int dc  = deg < CAP ? deg : CAP;
    int myc = csr[(size_t)r * CAP + l];

    const uint4* ybq = (const uint4*)yb;
    float s[8];
#pragma unroll
    for (int q = 0; q < 8; q++) s[q] = 0.f;

    bool valid = grp < dc;              // prefetch batch 0
    {
        int c0 = __shfl(myc, grp);
        int cs = valid ? c0 : 0;
        uint4 v = ybq[(size_t)cs * 8 + sub];
        for (int jb = 8; jb < dc; jb += 8) {
            int  j2     = jb + grp;
            int  c2     = __shfl(myc, j2);
            bool valid2 = j2 < dc;
            int  cs2    = valid2 ? c2 : 0;
            uint4 v2 = ybq[(size_t)cs2 * 8 + sub];     // next batch in flight
            if (valid) {
                s[0] += bf_lo(v.x); s[1] += bf_hi(v.x);
                s[2] += bf_lo(v.y); s[3] += bf_hi(v.y);
                s[4] += bf_lo(v.z); s[5] += bf_hi(v.z);
                s[6] += bf_lo(v.w); s[7] += bf_hi(v.w);
            }
            v = v2; valid = valid2;
        }
        if (valid) {
            s[0] += bf_lo(v.x); s[1] += bf_hi(v.x);
            s[2] += bf_lo(v.y); s[3] += bf_hi(v.y);
            s[4] += bf_lo(v.z); s[5] += bf_hi(v.z);
            s[6] += bf_lo(v.w); s[7] += bf_hi(v.w);
        }
    }
#pragma unroll
    for (int q = 0; q < 8; q++) {       // fold edge groups (lane bits 3..5)
        s[q] += __shfl_xor(s[q], 8);
        s[q] += __shfl_xor(s[q], 16);
        s[q] += __shfl_xor(s[q], 32);
    }

    if (grp == 0) {                     // lanes 0-7 write the full 256B row
        float inv_d = 1.0f / ((float)deg + 1e-6f);
        float4 b0 = ((const float4*)bias)[2 * sub];
        float4 b1 = ((const float4*)bias)[2 * sub + 1];
        float4 o0 = make_float4(s[0] * inv_d + b0.x, s[1] * inv_d + b0.y,
                                s[2] * inv_d + b0.z, s[3] * inv_d + b0.w);
        float4 o1 = make_float4(s[4] * inv_d + b1.x, s[5] * inv_d + b1.y,
                                s[6] * inv_d + b1.z, s[7] * inv_d + b1.w);
        ((float4*)(out + (size_t)r * DIM))[2 * sub]     = o0;
        ((float4*)(out + (size_t)r * DIM))[2 * sub + 1] = o1;
    }
}

extern "C" void kernel_launch(void* const* d_in, const int* in_sizes, int n_in,
                              void* d_out, int out_size, void* d_ws, size_t ws_size,
                              hipStream_t stream) {
    const float* x    = (const float*)d_in[0];
    const int*   ei   = (const int*)d_in[1];
    const float* W    = (const float*)d_in[2];
    const float* bias = (const float*)d_in[3];
    float* out = (float*)d_out;

    int*            count = (int*)d_ws;                                // 200 KB
    unsigned short* yb    = (unsigned short*)((char*)d_ws + 262144);   // 6.4 MB
    int*            csr   = (int*)d_out;                               // aliased

    hipMemsetAsync(count, 0, N_NODES * sizeof(int), stream);           // capture-legal
    place_gemm_kernel<<<TOTAL_BLOCKS, NTHR, 0, stream>>>(ei, x, W, count, csr, yb);
    agg_kernel<<<8 * 1563, NTHR, 0, stream>>>(yb, count, csr, bias, out);
}

// Round 5
// 129.631 us; speedup vs baseline: 1.0476x; 1.0476x over previous
//
#include <hip/hip_runtime.h>
#include <hip/hip_bf16.h>

#define N_NODES 50000
#define DIM 64
#define N_EDGES 800000
#define CAP 64          // padded-CSR capacity; P(deg>64) for Poisson(16) ~ e^-125
#define NTHR 256
#define GB_ROWS 32      // y-GEMM rows per block
#define SLICE 6250      // N_NODES / 8 rows per XCD slice
#define NGROUP 196      // 24-block groups: 8 GEMM + 16 place (2 chunks x 8 slices)
#define TOTAL_BLOCKS (NGROUP * 24)      // 4704
#define CHUNK_EDGES 2048                // per place-chunk; 392 chunks cover 800k

// ws layout: count[N_NODES] int @0 (200KB); yb bf16[N*DIM] @256KB (6.4MB);
// wpk uint4[512] @6815744 (8KB, prepacked swizzled W image);
// csr16 u16[N*CAP] @8388608 (6.4MB). Total ~14.8MB << ws.
// [R4 lesson: slice-partitioned place is load-bearing — unpartitioned scatter
//  dirties the same csr/count lines from 8 XCDs: WRITE_SIZE 54MB, K1 49.5us
//  of coherence stall. Keep atomics/stores XCD-local.]
// [R2 lesson: no mega-fusion — regalloc collapse (VGPR=24, spills, 3.5x).]
// [R3 lesson: two-phase col-partitioned gather costs more than L2 wins.]

typedef __attribute__((ext_vector_type(8))) short bf16x8;   // 8 bf16 (4 VGPRs)
typedef __attribute__((ext_vector_type(4))) float f32x4;    // 4 fp32 acc

static __device__ inline unsigned int f2bf(float f) {
    __hip_bfloat16 h = __float2bfloat16(f);           // RNE
    return (unsigned int)*reinterpret_cast<unsigned short*>(&h);
}
static __device__ inline float bf_lo(unsigned int u) { return __uint_as_float(u << 16); }
static __device__ inline float bf_hi(unsigned int u) { return __uint_as_float(u & 0xffff0000u); }

// K0: zero count (blocks 0-195) + prepack W into the swizzled bf16 LDS image
// (block 196). Replaces the hipMemsetAsync dispatch — same dispatch count.
__global__ __launch_bounds__(NTHR) void init_kernel(
    const float* __restrict__ W, int* __restrict__ count,
    uint4* __restrict__ wpk)
{
    int t = threadIdx.x, b = blockIdx.x;
    if (b < 196) {
        int i = b * NTHR + t;                   // 196*256 = 50176 >= 50000
        if (i < N_NODES) count[i] = 0;
    } else {
        for (int i = t; i < 512; i += NTHR) {   // n = i>>3, kgrp = i&7
            int n = i >> 3, kg = i & 7;
            const float* wr = W + n * DIM + kg * 8;     // 8 contiguous k
            uint4 uw;
            uw.x = f2bf(wr[0]) | (f2bf(wr[1]) << 16);
            uw.y = f2bf(wr[2]) | (f2bf(wr[3]) << 16);
            uw.z = f2bf(wr[4]) | (f2bf(wr[5]) << 16);
            uw.w = f2bf(wr[6]) | (f2bf(wr[7]) << 16);
            wpk[(n << 3) | (kg ^ (n & 7))] = uw;        // XOR-swizzled slot
        }
    }
}

// K1 (interleaved block-specialization, XCD-partitioned place):
//   b%24 <  8 -> y = x @ W^T via v_mfma_f32_16x16x32_bf16 (32 rows/block).
//                x hi/lo-split (bf16 pair) => fp32-x * bf16-W in fp32 acc.
//                W tile = straight 8KB copy of the prepacked image (R5).
//   b%24 >= 8 -> place: scan a 2048-edge chunk (int4 row stream, 8 edges/
//                thread), keep rows in slice b%8 (sub+cmp). All atomics and
//                u16 csr stores for slice s issue from one XCD (b%8 round-
//                robin heuristic) -> count/csr lines stay in one L2.
__global__ __launch_bounds__(NTHR, 8) void place_gemm_kernel(
    const int* __restrict__ ei, const float* __restrict__ x,
    const uint4* __restrict__ wpk, int* __restrict__ count,
    unsigned short* __restrict__ csr16, unsigned short* __restrict__ yb)
{
    __shared__ float4 xs4[GB_ROWS * 16];    // 8 KB fp32 x rows, slot c^(m&15)
    __shared__ uint4  Wb[512];              // 8 KB bf16 W, [n][kg^(n&7)] short8

    int t = threadIdx.x;
    int b = blockIdx.x;
    int m = b % 24;

    if (m < 8) {
        // ---- y-GEMM side: g = (b/24)*8 + m in [0, 1568); active g < 1563 ----
        int g  = (b / 24) * 8 + m;
        int R0 = g * GB_ROWS;
        if (R0 < N_NODES) {                 // block-uniform; tail slots exit
            const float4* x4 = (const float4*)x;
            for (int i = t; i < GB_ROWS * 16; i += NTHR) {
                int r = i >> 4, c = i & 15;
                int q = (R0 + r) * 16 + c;
                float4 v = (q < N_NODES * 16) ? x4[q]
                                              : make_float4(0.f, 0.f, 0.f, 0.f);
                xs4[(r << 4) | (c ^ (r & 15))] = v;     // XOR-swizzled slot
            }
            for (int i = t; i < 512; i += NTHR)         // 8KB image copy
                Wb[i] = wpk[i];
            __syncthreads();

            int w  = t >> 6, l = t & 63;
            int rt = w >> 1, ch = w & 1;    // row-tile (16 rows), col-half (32)
            int lm = l & 15, lg = l >> 4;   // frag row/col lane, k-group lane
            int mloc = rt * 16 + lm;        // local A row 0..31

            f32x4 acc0 = {0.f, 0.f, 0.f, 0.f};
            f32x4 acc1 = {0.f, 0.f, 0.f, 0.f};
#pragma unroll
            for (int kc = 0; kc < 2; kc++) {            // K = 64 in 2 chunks
                int c0 = kc * 8 + lg * 2;               // float4 slot index
                float4 xa = xs4[(mloc << 4) | ((c0    ) ^ lm)];
                float4 xb = xs4[(mloc << 4) | ((c0 + 1) ^ lm)];
                float xv[8] = {xa.x, xa.y, xa.z, xa.w, xb.x, xb.y, xb.z, xb.w};
                bf16x8 ahi, alo;                        // hi/lo split of x
#pragma unroll
                for (int j = 0; j < 8; j++) {
                    unsigned hb = f2bf(xv[j]);
                    float lo = xv[j] - __uint_as_float(hb << 16);
                    ahi[j] = (short)hb;
                    alo[j] = (short)f2bf(lo);
                }
                int kgg = kc * 4 + lg;                  // global k-group 0..7
#pragma unroll
                for (int ctl = 0; ctl < 2; ctl++) {     // 2 col-tiles per wave
                    int n = (ch * 2 + ctl) * 16 + lm;   // B col == W row
                    uint4 wq = Wb[(n << 3) | (kgg ^ (n & 7))];
                    bf16x8 bfr = *reinterpret_cast<bf16x8*>(&wq);
                    if (ctl == 0) {
                        acc0 = __builtin_amdgcn_mfma_f32_16x16x32_bf16(ahi, bfr, acc0, 0, 0, 0);
                        acc0 = __builtin_amdgcn_mfma_f32_16x16x32_bf16(alo, bfr, acc0, 0, 0, 0);
                    } else {
                        acc1 = __builtin_amdgcn_mfma_f32_16x16x32_bf16(ahi, bfr, acc1, 0, 0, 0);
                        acc1 = __builtin_amdgcn_mfma_f32_16x16x32_bf16(alo, bfr, acc1, 0, 0, 0);
                    }
                }
            }
            // C/D layout: col = lane&15, row = (lane>>4)*4 + reg  [m89/m91]
#pragma unroll
            for (int ctl = 0; ctl < 2; ctl++) {
                f32x4 acc = ctl ? acc1 : acc0;
                int n = (ch * 2 + ctl) * 16 + lm;
#pragma unroll
                for (int q = 0; q < 4; q++) {
                    int rr = R0 + rt * 16 + lg * 4 + q;
                    if (rr < N_NODES)
                        yb[(size_t)rr * DIM + n] = (unsigned short)f2bf(acc[q]);
                }
            }
        }
    } else {
        // ---- place side: slice s = b&7, chunk q; 8 edges/thread via int4 ----
        int s    = b & 7;
        int lo   = s * SLICE;
        int q    = (b / 24) * 2 + ((m - 8) >> 3);     // 0..391
        int e0   = q * CHUNK_EDGES + t * 8;           // 8-aligned; 800000%8==0
        if (e0 < N_EDGES) {                           // whole group in or out
            const int4* rp = (const int4*)(ei + e0);
            int4 ra = rp[0];
            int4 rb = rp[1];
            int rows[8] = {ra.x, ra.y, ra.z, ra.w, rb.x, rb.y, rb.z, rb.w};
#pragma unroll
            for (int k = 0; k < 8; k++) {
                if ((unsigned)(rows[k] - lo) < (unsigned)SLICE) {
                    int col = ei[N_EDGES + e0 + k];
                    int pos = atomicAdd(&count[rows[k]], 1);   // XCD-local L2
                    if (pos < CAP)
                        csr16[rows[k] * CAP + pos] = (unsigned short)col;
                }
            }
        }
    }
}

// K2: gather-mean over bf16 y + bias. 1 row/wave, slice-mapped (sb=bid&7)
// so csr/count/out traffic stays XCD-affine. Gather software-pipelined
// 2-deep. csr16 lives in ws (no d_out aliasing — no ordering hazard).
__global__ __launch_bounds__(NTHR) void agg_kernel(
    const unsigned short* __restrict__ yb, const int* __restrict__ count,
    const unsigned short* __restrict__ csr16, const float* __restrict__ bias,
    float* __restrict__ out)
{
    int t   = threadIdx.x;
    int w   = t >> 6;
    int l   = t & 63;
    int sub = l & 7;                    // which 16B (8 feats) of the 128B row
    int grp = l >> 3;                   // edge group 0..7
    int sb  = blockIdx.x & 7;           // row slice
    int i   = blockIdx.x >> 3;          // 0..1562
    int rl  = i * 4 + w;
    if (rl >= SLICE) return;            // tail guard
    int r = sb * SLICE + rl;

    int deg = count[r];
    int dc  = deg < CAP ? deg : CAP;
    int myc = csr16[(size_t)r * CAP + l];   // 128B/wave coalesced u16

    const uint4* ybq = (const uint4*)yb;
    float s[8];
#pragma unroll
    for (int q = 0; q < 8; q++) s[q] = 0.f;

    bool valid = grp < dc;              // prefetch batch 0
    {
        int c0 = __shfl(myc, grp);
        int cs = valid ? c0 : 0;
        uint4 v = ybq[(size_t)cs * 8 + sub];
        for (int jb = 8; jb < dc; jb += 8) {
            int  j2     = jb + grp;
            int  c2     = __shfl(myc, j2);
            bool valid2 = j2 < dc;
            int  cs2    = valid2 ? c2 : 0;
            uint4 v2 = ybq[(size_t)cs2 * 8 + sub];     // next batch in flight
            if (valid) {
                s[0] += bf_lo(v.x); s[1] += bf_hi(v.x);
                s[2] += bf_lo(v.y); s[3] += bf_hi(v.y);
                s[4] += bf_lo(v.z); s[5] += bf_hi(v.z);
                s[6] += bf_lo(v.w); s[7] += bf_hi(v.w);
            }
            v = v2; valid = valid2;
        }
        if (valid) {
            s[0] += bf_lo(v.x); s[1] += bf_hi(v.x);
            s[2] += bf_lo(v.y); s[3] += bf_hi(v.y);
            s[4] += bf_lo(v.z); s[5] += bf_hi(v.z);
            s[6] += bf_lo(v.w); s[7] += bf_hi(v.w);
        }
    }
#pragma unroll
    for (int q = 0; q < 8; q++) {       // fold edge groups (lane bits 3..5)
        s[q] += __shfl_xor(s[q], 8);
        s[q] += __shfl_xor(s[q], 16);
        s[q] += __shfl_xor(s[q], 32);
    }

    if (grp == 0) {                     // lanes 0-7 write the full 256B row
        float inv_d = 1.0f / ((float)deg + 1e-6f);
        float4 b0 = ((const float4*)bias)[2 * sub];
        float4 b1 = ((const float4*)bias)[2 * sub + 1];
        float4 o0 = make_float4(s[0] * inv_d + b0.x, s[1] * inv_d + b0.y,
                                s[2] * inv_d + b0.z, s[3] * inv_d + b0.w);
        float4 o1 = make_float4(s[4] * inv_d + b1.x, s[5] * inv_d + b1.y,
                                s[6] * inv_d + b1.z, s[7] * inv_d + b1.w);
        ((float4*)(out + (size_t)r * DIM))[2 * sub]     = o0;
        ((float4*)(out + (size_t)r * DIM))[2 * sub + 1] = o1;
    }
}

extern "C" void kernel_launch(void* const* d_in, const int* in_sizes, int n_in,
                              void* d_out, int out_size, void* d_ws, size_t ws_size,
                              hipStream_t stream) {
    const float* x    = (const float*)d_in[0];
    const int*   ei   = (const int*)d_in[1];
    const float* W    = (const float*)d_in[2];
    const float* bias = (const float*)d_in[3];
    float* out = (float*)d_out;

    int*            count = (int*)d_ws;                                  // 200 KB @0
    unsigned short* yb    = (unsigned short*)((char*)d_ws + 262144);     // 6.4 MB
    uint4*          wpk   = (uint4*)((char*)d_ws + 6815744);             // 8 KB
    unsigned short* csr16 = (unsigned short*)((char*)d_ws + 8388608);    // 6.4 MB

    init_kernel<<<197, NTHR, 0, stream>>>(W, count, wpk);
    place_gemm_kernel<<<TOTAL_BLOCKS, NTHR, 0, stream>>>(ei, x, wpk, count, csr16, yb);
    agg_kernel<<<8 * 1563, NTHR, 0, stream>>>(yb, count, csr16, bias, out);
}

// Round 6
// 128.253 us; speedup vs baseline: 1.0589x; 1.0107x over previous
//
#include <hip/hip_runtime.h>
#include <hip/hip_bf16.h>

#define N_NODES 50000
#define DIM 64
#define N_EDGES 800000
#define CAP 64          // padded-CSR capacity; P(deg>64) for Poisson(16) ~ e^-125
#define NTHR 256
#define GB_ROWS 32      // y-GEMM rows per block
#define SLICE 6250      // N_NODES / 8 rows per XCD slice
#define NGROUP 196      // 24-block groups: 8 GEMM + 16 place (2 chunks x 8 slices)
#define TOTAL_BLOCKS (NGROUP * 24)      // 4704
#define CHUNK_EDGES 2048                // per place-chunk; 392 chunks cover 800k
#define PACK_BLOCKS 782                 // 800000/4 quads / 256 threads

// ws layout: count[N_NODES] int @0 (200KB); yb bf16[N*DIM] @256KB (6.4MB);
// wpk uint4[512] @6815744 (8KB swizzled W image); pack u32[N_EDGES] @8388608
// (3.2MB, row|col<<16); csr16 u16[N*CAP] @12582912 (6.4MB). ~19MB << ws.
// Budget (R0-R5): ~92us in-region poison fills (fixed) + ~37us addressable.
// [R4 lesson: slice-partitioned place is load-bearing — unpartitioned scatter
//  = 54MB WRITE_SIZE coherence thrash, K1 49.5us. Keep atomics XCD-local.]
// [R2 lesson: no mega-fusion — regalloc collapse (VGPR=24, spills, 3.5x).]
// [R3 lesson: two-phase col-partitioned gather costs more than L2 wins.]
// [R5 lesson: u16 csr + W-prepack = noise-level; K1 not store-BW-bound.]

typedef __attribute__((ext_vector_type(8))) short bf16x8;   // 8 bf16 (4 VGPRs)
typedef __attribute__((ext_vector_type(4))) float f32x4;    // 4 fp32 acc

static __device__ inline unsigned int f2bf(float f) {
    __hip_bfloat16 h = __float2bfloat16(f);           // RNE
    return (unsigned int)*reinterpret_cast<unsigned short*>(&h);
}
static __device__ inline float bf_lo(unsigned int u) { return __uint_as_float(u << 16); }
static __device__ inline float bf_hi(unsigned int u) { return __uint_as_float(u & 0xffff0000u); }

// K0: zero count (blocks 0-195), prepack W (block 196), pack edges into
// u32 row|col<<16 (blocks 197..978) so place reads ONE coalesced stream
// instead of rows + line-granular scattered col fetches.
__global__ __launch_bounds__(NTHR) void init_kernel(
    const float* __restrict__ W, const int* __restrict__ ei,
    int* __restrict__ count, uint4* __restrict__ wpk,
    unsigned int* __restrict__ pack)
{
    int t = threadIdx.x, b = blockIdx.x;
    if (b < 196) {
        int i = b * NTHR + t;                   // 196*256 = 50176 >= 50000
        if (i < N_NODES) count[i] = 0;
    } else if (b == 196) {
        for (int i = t; i < 512; i += NTHR) {   // n = i>>3, kgrp = i&7
            int n = i >> 3, kg = i & 7;
            const float* wr = W + n * DIM + kg * 8;     // 8 contiguous k
            uint4 uw;
            uw.x = f2bf(wr[0]) | (f2bf(wr[1]) << 16);
            uw.y = f2bf(wr[2]) | (f2bf(wr[3]) << 16);
            uw.z = f2bf(wr[4]) | (f2bf(wr[5]) << 16);
            uw.w = f2bf(wr[6]) | (f2bf(wr[7]) << 16);
            wpk[(n << 3) | (kg ^ (n & 7))] = uw;        // XOR-swizzled slot
        }
    } else {
        int gid = (b - 197) * NTHR + t;         // one int4-quad (4 edges)
        if (gid * 4 < N_EDGES) {                // 800000%4==0: whole quads
            int4 r4 = ((const int4*)ei)[gid];
            int4 c4 = ((const int4*)(ei + N_EDGES))[gid];
            uint4 o;
            o.x = (unsigned)r4.x | ((unsigned)c4.x << 16);
            o.y = (unsigned)r4.y | ((unsigned)c4.y << 16);
            o.z = (unsigned)r4.z | ((unsigned)c4.z << 16);
            o.w = (unsigned)r4.w | ((unsigned)c4.w << 16);
            ((uint4*)pack)[gid] = o;
        }
    }
}

// K1 (interleaved block-specialization, XCD-partitioned place, LDS-FREE):
//   b%24 <  8 -> y = x @ W^T via v_mfma_f32_16x16x32_bf16 (32 rows/block).
//                A-frag = 2 direct float4 global loads (8 contiguous fp32 of
//                one x row — wave footprint is a contiguous 2KB slab);
//                B-frag = direct load from the 8KB wpk image (L1-resident).
//                No LDS, no barrier. x hi/lo-split => fp32-x * bf16-W in
//                fp32 acc. Rows >= N clamp to row 0; their stores are guarded.
//   b%24 >= 8 -> place: scan a 2048-edge chunk of the PACKED stream (int4,
//                8 edges/thread), keep rows in slice b%8 (sub+cmp). All
//                atomics + u16 csr stores for slice s issue from one XCD
//                (b%8 round-robin heuristic) -> count/csr lines in one L2.
__global__ __launch_bounds__(NTHR, 8) void place_gemm_kernel(
    const unsigned int* __restrict__ pack, const float* __restrict__ x,
    const uint4* __restrict__ wpk, int* __restrict__ count,
    unsigned short* __restrict__ csr16, unsigned short* __restrict__ yb)
{
    int t = threadIdx.x;
    int b = blockIdx.x;
    int m = b % 24;

    if (m < 8) {
        // ---- y-GEMM side: g = (b/24)*8 + m in [0, 1568); active g < 1563 ----
        int g  = (b / 24) * 8 + m;
        int R0 = g * GB_ROWS;
        if (R0 < N_NODES) {                 // block-uniform; tail slots exit
            int w  = t >> 6, l = t & 63;
            int rt = w >> 1, ch = w & 1;    // row-tile (16 rows), col-half (32)
            int lm = l & 15, lg = l >> 4;   // frag row/col lane, k-group lane
            int r  = R0 + rt * 16 + lm;     // this lane's A row
            int rc = r < N_NODES ? r : 0;   // clamp OOB rows (stores guarded)
            const float4* xr = (const float4*)(x + (size_t)rc * DIM);

            f32x4 acc0 = {0.f, 0.f, 0.f, 0.f};
            f32x4 acc1 = {0.f, 0.f, 0.f, 0.f};
#pragma unroll
            for (int kc = 0; kc < 2; kc++) {            // K = 64 in 2 chunks
                float4 xa = xr[kc * 8 + lg * 2];        // 8 contiguous fp32
                float4 xb = xr[kc * 8 + lg * 2 + 1];
                float xv[8] = {xa.x, xa.y, xa.z, xa.w, xb.x, xb.y, xb.z, xb.w};
                bf16x8 ahi, alo;                        // hi/lo split of x
#pragma unroll
                for (int j = 0; j < 8; j++) {
                    unsigned hb = f2bf(xv[j]);
                    float lo = xv[j] - __uint_as_float(hb << 16);
                    ahi[j] = (short)hb;
                    alo[j] = (short)f2bf(lo);
                }
                int kgg = kc * 4 + lg;                  // global k-group 0..7
#pragma unroll
                for (int ctl = 0; ctl < 2; ctl++) {     // 2 col-tiles per wave
                    int n = (ch * 2 + ctl) * 16 + lm;   // B col == W row
                    uint4 wq = wpk[(n << 3) | (kgg ^ (n & 7))];
                    bf16x8 bfr = *reinterpret_cast<bf16x8*>(&wq);
                    if (ctl == 0) {
                        acc0 = __builtin_amdgcn_mfma_f32_16x16x32_bf16(ahi, bfr, acc0, 0, 0, 0);
                        acc0 = __builtin_amdgcn_mfma_f32_16x16x32_bf16(alo, bfr, acc0, 0, 0, 0);
                    } else {
                        acc1 = __builtin_amdgcn_mfma_f32_16x16x32_bf16(ahi, bfr, acc1, 0, 0, 0);
                        acc1 = __builtin_amdgcn_mfma_f32_16x16x32_bf16(alo, bfr, acc1, 0, 0, 0);
                    }
                }
            }
            // C/D layout: col = lane&15, row = (lane>>4)*4 + reg  [m89/m91]
#pragma unroll
            for (int ctl = 0; ctl < 2; ctl++) {
                f32x4 acc = ctl ? acc1 : acc0;
                int n = (ch * 2 + ctl) * 16 + lm;
#pragma unroll
                for (int q = 0; q < 4; q++) {
                    int rr = R0 + rt * 16 + lg * 4 + q;
                    if (rr < N_NODES)
                        yb[(size_t)rr * DIM + n] = (unsigned short)f2bf(acc[q]);
                }
            }
        }
    } else {
        // ---- place side: slice s = b&7, chunk q; 8 edges/thread via int4 ----
        int s    = b & 7;
        int lo   = s * SLICE;
        int q    = (b / 24) * 2 + ((m - 8) >> 3);     // 0..391
        int e0   = q * CHUNK_EDGES + t * 8;           // 8-aligned; 800000%8==0
        if (e0 < N_EDGES) {                           // whole group in or out
            const uint4* pp = (const uint4*)(pack + e0);
            uint4 pa = pp[0];
            uint4 pb = pp[1];
            unsigned pk[8] = {pa.x, pa.y, pa.z, pa.w, pb.x, pb.y, pb.z, pb.w};
#pragma unroll
            for (int k = 0; k < 8; k++) {
                int row = (int)(pk[k] & 0xffffu);
                if ((unsigned)(row - lo) < (unsigned)SLICE) {
                    int col = (int)(pk[k] >> 16);              // in-register
                    int pos = atomicAdd(&count[row], 1);       // XCD-local L2
                    if (pos < CAP)
                        csr16[row * CAP + pos] = (unsigned short)col;
                }
            }
        }
    }
}

// K2: gather-mean over bf16 y + bias. 1 row/wave, slice-mapped (sb=bid&7)
// so csr/count/out traffic stays XCD-affine. Gather software-pipelined
// 2-deep. [R5 floor arithmetic: 102MB random gather at L3 BW + 12.8MB out
// write ~= 10us; VALU only ~1.3us — lane restructuring buys nothing.]
__global__ __launch_bounds__(NTHR) void agg_kernel(
    const unsigned short* __restrict__ yb, const int* __restrict__ count,
    const unsigned short* __restrict__ csr16, const float* __restrict__ bias,
    float* __restrict__ out)
{
    int t   = threadIdx.x;
    int w   = t >> 6;
    int l   = t & 63;
    int sub = l & 7;                    // which 16B (8 feats) of the 128B row
    int grp = l >> 3;                   // edge group 0..7
    int sb  = blockIdx.x & 7;           // row slice
    int i   = blockIdx.x >> 3;          // 0..1562
    int rl  = i * 4 + w;
    if (rl >= SLICE) return;            // tail guard
    int r = sb * SLICE + rl;

    int deg = count[r];
    int dc  = deg < CAP ? deg : CAP;
    int myc = csr16[(size_t)r * CAP + l];   // 128B/wave coalesced u16

    const uint4* ybq = (const uint4*)yb;
    float s[8];
#pragma unroll
    for (int q = 0; q < 8; q++) s[q] = 0.f;

    bool valid = grp < dc;              // prefetch batch 0
    {
        int c0 = __shfl(myc, grp);
        int cs = valid ? c0 : 0;
        uint4 v = ybq[(size_t)cs * 8 + sub];
        for (int jb = 8; jb < dc; jb += 8) {
            int  j2     = jb + grp;
            int  c2     = __shfl(myc, j2);
            bool valid2 = j2 < dc;
            int  cs2    = valid2 ? c2 : 0;
            uint4 v2 = ybq[(size_t)cs2 * 8 + sub];     // next batch in flight
            if (valid) {
                s[0] += bf_lo(v.x); s[1] += bf_hi(v.x);
                s[2] += bf_lo(v.y); s[3] += bf_hi(v.y);
                s[4] += bf_lo(v.z); s[5] += bf_hi(v.z);
                s[6] += bf_lo(v.w); s[7] += bf_hi(v.w);
            }
            v = v2; valid = valid2;
        }
        if (valid) {
            s[0] += bf_lo(v.x); s[1] += bf_hi(v.x);
            s[2] += bf_lo(v.y); s[3] += bf_hi(v.y);
            s[4] += bf_lo(v.z); s[5] += bf_hi(v.z);
            s[6] += bf_lo(v.w); s[7] += bf_hi(v.w);
        }
    }
#pragma unroll
    for (int q = 0; q < 8; q++) {       // fold edge groups (lane bits 3..5)
        s[q] += __shfl_xor(s[q], 8);
        s[q] += __shfl_xor(s[q], 16);
        s[q] += __shfl_xor(s[q], 32);
    }

    if (grp == 0) {                     // lanes 0-7 write the full 256B row
        float inv_d = 1.0f / ((float)deg + 1e-6f);
        float4 b0 = ((const float4*)bias)[2 * sub];
        float4 b1 = ((const float4*)bias)[2 * sub + 1];
        float4 o0 = make_float4(s[0] * inv_d + b0.x, s[1] * inv_d + b0.y,
                                s[2] * inv_d + b0.z, s[3] * inv_d + b0.w);
        float4 o1 = make_float4(s[4] * inv_d + b1.x, s[5] * inv_d + b1.y,
                                s[6] * inv_d + b1.z, s[7] * inv_d + b1.w);
        ((float4*)(out + (size_t)r * DIM))[2 * sub]     = o0;
        ((float4*)(out + (size_t)r * DIM))[2 * sub + 1] = o1;
    }
}

extern "C" void kernel_launch(void* const* d_in, const int* in_sizes, int n_in,
                              void* d_out, int out_size, void* d_ws, size_t ws_size,
                              hipStream_t stream) {
    const float* x    = (const float*)d_in[0];
    const int*   ei   = (const int*)d_in[1];
    const float* W    = (const float*)d_in[2];
    const float* bias = (const float*)d_in[3];
    float* out = (float*)d_out;

    int*            count = (int*)d_ws;                                  // 200 KB @0
    unsigned short* yb    = (unsigned short*)((char*)d_ws + 262144);     // 6.4 MB
    uint4*          wpk   = (uint4*)((char*)d_ws + 6815744);             // 8 KB
    unsigned int*   pack  = (unsigned int*)((char*)d_ws + 8388608);      // 3.2 MB
    unsigned short* csr16 = (unsigned short*)((char*)d_ws + 12582912);   // 6.4 MB

    init_kernel<<<197 + PACK_BLOCKS, NTHR, 0, stream>>>(W, ei, count, wpk, pack);
    place_gemm_kernel<<<TOTAL_BLOCKS, NTHR, 0, stream>>>(pack, x, wpk, count, csr16, yb);
    agg_kernel<<<8 * 1563, NTHR, 0, stream>>>(yb, count, csr16, bias, out);
}